// Round 10
// baseline (179.454 us; speedup 1.0000x reference)
//
#include <hip/hip_runtime.h>

// Problem constants
#define E_  100
#define F_  10
#define D_  100
#define N_  8192
#define TN  256          // n-rows per mono/z block
#define NTILES (N_ / TN) // 32

typedef float f32x4 __attribute__((ext_vector_type(4)));

// Combined params per estimator (floats), stride WS_PER_E:
//   [0..199] Whi (2x100 a-major) [200..299] bhi
//   [300..499] Wlo               [500..599] blo
//   [600..619] Wenc (10x2 f-major) [620..621] benc
#define WS_PER_E 624
#define CMB_FLOATS (E_ * WS_PER_E)          // 62,400
#define Z_FLOATS   (2 * E_ * N_)            // 1,638,400
#define T_FLOATS   (D_ * N_)                // 819,200

// Dense-front store engine geometry
#define NB_STORE   2048                     // resident blocks (8/CU)
#define CHUNK_FL   1600                     // floats per chunk = 16 rows x 100
#define NCHUNK     (2 * E_ * N_ * D_ / CHUNK_FL)   // 102,400

// ---------------------------------------------------------------------------
// Prep kernel: blocks 0..99 fold estimator MLPs into affine maps (-> cmb);
// blocks 100..355 transpose inputs into T (128n x 25d tiles). 128 threads.
// ---------------------------------------------------------------------------
template <bool DO_TRANSPOSE>
__global__ __launch_bounds__(128) void prep_kernel(
    const float* __restrict__ inputs,
    const float* __restrict__ enc_w0, const float* __restrict__ enc_b0,
    const float* __restrict__ enc_w1, const float* __restrict__ enc_b1,
    const float* __restrict__ enc_w2, const float* __restrict__ enc_b2,
    const float* __restrict__ hi_w0,  const float* __restrict__ hi_b0,
    const float* __restrict__ hi_w1,  const float* __restrict__ hi_b1,
    const float* __restrict__ hi_w2,  const float* __restrict__ hi_b2,
    const float* __restrict__ lo_w0,  const float* __restrict__ lo_b0,
    const float* __restrict__ lo_w1,  const float* __restrict__ lo_b1,
    const float* __restrict__ lo_w2,  const float* __restrict__ lo_b2,
    float* __restrict__ cmb, float* __restrict__ T)
{
    const int t = threadIdx.x;

    if (DO_TRANSPOSE && blockIdx.x >= E_) {
        const int bi = blockIdx.x - E_;          // 0..255
        const int n0 = (bi >> 2) * 128;
        const int d0 = (bi & 3) * 25;
        const float* rowp = inputs + (size_t)(n0 + t) * D_ + d0;
#pragma unroll 5
        for (int j = 0; j < 25; ++j)
            T[(size_t)(d0 + j) * N_ + n0 + t] = rowp[j];
        return;
    }

    const int e = blockIdx.x;
    float* wsE = cmb + (size_t)e * WS_PER_E;

    // ---------------- encoder: (10x5)@(5x2)@(2x2) -------------------------
    {
        const float* w0 = enc_w0 + e * 50;  // 10x5
        const float* w1 = enc_w1 + e * 10;  // 5x2
        const float* w2 = enc_w2 + e * 4;   // 2x2
        const float* b0 = enc_b0 + e * 5;
        const float* b1 = enc_b1 + e * 2;
        const float* b2 = enc_b2 + e * 2;

        __shared__ float sW01[20];
        __shared__ float sB01[2];
        if (t < 20) {
            int f = t >> 1, g = t & 1;
            float s = 0.f;
            for (int k = 0; k < 5; ++k) s += w0[f * 5 + k] * w1[k * 2 + g];
            sW01[t] = s;
        }
        if (t < 2) {
            float s = b1[t];
            for (int k = 0; k < 5; ++k) s += b0[k] * w1[k * 2 + t];
            sB01[t] = s;
        }
        __syncthreads();
        if (t < 20) {
            int f = t >> 1, g2 = t & 1;
            wsE[600 + t] = sW01[f * 2 + 0] * w2[0 * 2 + g2]
                         + sW01[f * 2 + 1] * w2[1 * 2 + g2];
        }
        if (t < 2) {
            wsE[620 + t] = sB01[0] * w2[0 * 2 + t] + sB01[1] * w2[1 * 2 + t] + b2[t];
        }
        __syncthreads();
    }

    // ---------------- decoders: (2x25)@(25x50)@(50x100) -------------------
    __shared__ float sT[100];
    __shared__ float sU[50];
    for (int dec = 0; dec < 2; ++dec) {
        const float* w0 = (dec ? lo_w0 : hi_w0) + e * 50;
        const float* w1 = (dec ? lo_w1 : hi_w1) + e * 1250;
        const float* w2 = (dec ? lo_w2 : hi_w2) + e * 5000;
        const float* b0 = (dec ? lo_b0 : hi_b0) + e * 25;
        const float* b1 = (dec ? lo_b1 : hi_b1) + e * 50;
        const float* b2 = (dec ? lo_b2 : hi_b2) + e * 100;
        float* W = wsE + (dec ? 300 : 0);
        float* B = wsE + (dec ? 500 : 200);

        for (int i = t; i < 100; i += blockDim.x) {
            int a = i / 50, c = i % 50;
            float s = 0.f;
            for (int b = 0; b < 25; ++b) s += w0[a * 25 + b] * w1[b * 50 + c];
            sT[i] = s;
        }
        for (int i = t; i < 50; i += blockDim.x) {
            float s = b1[i];
            for (int b = 0; b < 25; ++b) s += b0[b] * w1[b * 50 + i];
            sU[i] = s;
        }
        __syncthreads();
        for (int i = t; i < 200; i += blockDim.x) {
            int a = i / 100, d = i % 100;
            float s = 0.f;
            for (int c = 0; c < 50; ++c) s += sT[a * 50 + c] * w2[c * 100 + d];
            W[i] = s;
        }
        for (int i = t; i < 100; i += blockDim.x) {
            float s = b2[i];
            for (int c = 0; c < 50; ++c) s += sU[c] * w2[c * 100 + i];
            B[i] = s;
        }
        __syncthreads();
    }
}

// ---------------------------------------------------------------------------
// z kernel: z[e][n] = xg . Wenc + benc, coalesced via transposed inputs.
// ---------------------------------------------------------------------------
__global__ __launch_bounds__(256) void z_kernel(
    const float* __restrict__ cmb, const int* __restrict__ randsamples,
    const float* __restrict__ T, float2* __restrict__ zbuf)
{
    const int e    = blockIdx.x >> 5;
    const int tile = blockIdx.x & (NTILES - 1);
    const int n0   = tile * TN;
    const int t    = threadIdx.x;

    __shared__ float sW[22];   // Wenc(20) + benc(2)
    __shared__ int   sIdx[F_];
    if (t < 22) sW[t] = cmb[(size_t)e * WS_PER_E + 600 + t];
    if (t < F_) sIdx[t] = randsamples[e * F_ + t];
    __syncthreads();

    float z0 = sW[20];
    float z1 = sW[21];
#pragma unroll
    for (int f = 0; f < F_; ++f) {
        const float v = T[(size_t)sIdx[f] * N_ + n0 + t];
        z0 += v * sW[2 * f + 0];
        z1 += v * sW[2 * f + 1];
    }
    zbuf[(size_t)e * N_ + n0 + t] = make_float2(z0, z1);
}

// ---------------------------------------------------------------------------
// Store engine, DENSE GLOBAL FRONT: grid-stride over 6.4 KB chunks so that at
// any instant the ~2048 resident blocks write ADJACENT chunks -- one dense
// contiguous moving front (like the 6.8 TB/s fill), maximizing DRAM row-buffer
// locality. No LDS, no barriers; weights/z are small L2-hot re-reads.
//   chunk g -> eh = g>>9 (0..199), half = eh>=100, e = eh-100*half,
//              rows rb*16..rb*16+15 where rb = g & 511.
// ---------------------------------------------------------------------------
__global__ __launch_bounds__(256) void rancoders_store(
    const float* __restrict__ cmb, const float2* __restrict__ zbuf,
    float* __restrict__ out)
{
    const int t  = threadIdx.x;
    const int w  = t >> 6;           // wave 0..3
    const int l  = t & 63;
    const int h  = l >> 5;           // half-wave 0/1
    const int dq = l & 31;           // 0..31; 25..31 masked
    const bool act = (dq < 25);
    const int d  = (act ? dq : 24) * 4;
    const int rr = w * 4 + h;        // lane's first row in chunk (0..15)

#pragma unroll 2
    for (int g = blockIdx.x; g < NCHUNK; g += NB_STORE) {
        const int eh   = g >> 9;             // 0..199
        const int half = (eh >= E_) ? 1 : 0;
        const int e    = eh - half * E_;
        const int rb   = g & 511;
        const int n0c  = rb * 16;

        const float* cw = cmb + (size_t)e * WS_PER_E + (half ? 300 : 0);
        const f32x4 w0 = *(const f32x4*)&cw[d];
        const f32x4 w1 = *(const f32x4*)&cw[100 + d];
        const f32x4 bb = *(const f32x4*)&cw[200 + d];

        const float2 za = zbuf[(size_t)e * N_ + n0c + rr];
        const float2 zb = zbuf[(size_t)e * N_ + n0c + rr + 2];

        f32x4 oa = za.x * w0 + za.y * w1 + bb;
        f32x4 ob = zb.x * w0 + zb.y * w1 + bb;

        if (act) {
            float* dst = out + (size_t)g * CHUNK_FL + (size_t)rr * D_ + d;
            *(f32x4*)&dst[0]       = oa;
            *(f32x4*)&dst[2 * D_]  = ob;
        }
    }
}

// ---------------------------------------------------------------------------
// Fallback main (R4/R6-proven): per (e,tile) computes z inline, stores both
// halves. USE_T selects transposed-gather.
// ---------------------------------------------------------------------------
template <bool USE_T>
__global__ __launch_bounds__(256) void rancoders_mono(
    const float* __restrict__ inputs, const int* __restrict__ randsamples,
    const float* __restrict__ cmb, const float* __restrict__ T,
    float* __restrict__ out)
{
    const int e    = blockIdx.x >> 5;
    const int tile = blockIdx.x & (NTILES - 1);
    const int n0   = tile * TN;
    const int t    = threadIdx.x;

    __shared__ __align__(16) float sP[WS_PER_E];
    __shared__ int    sIdx[F_];
    __shared__ float2 sZ2[TN];

    const float* wsE = cmb + (size_t)e * WS_PER_E;
    for (int i = t; i < 622; i += 256) sP[i] = wsE[i];
    if (t < F_) sIdx[t] = randsamples[e * F_ + t];
    __syncthreads();

    {
        float z0 = sP[620], z1 = sP[621];
        if (USE_T) {
#pragma unroll
            for (int f = 0; f < F_; ++f) {
                float v = T[(size_t)sIdx[f] * N_ + n0 + t];
                z0 += v * sP[600 + 2 * f + 0];
                z1 += v * sP[600 + 2 * f + 1];
            }
        } else {
            const float* row = inputs + (size_t)(n0 + t) * D_;
#pragma unroll
            for (int f = 0; f < F_; ++f) {
                float v = row[sIdx[f]];
                z0 += v * sP[600 + 2 * f + 0];
                z1 += v * sP[600 + 2 * f + 1];
            }
        }
        sZ2[t] = make_float2(z0, z1);
    }
    __syncthreads();

    const int w    = t >> 6;
    const int l    = t & 63;
    const int h    = l >> 5;
    const int dq   = l & 31;
    const bool act = (dq < 25);
    const int d    = (act ? dq : 24) * 4;

    const f32x4 w0h = *(const f32x4*)&sP[0 + d];
    const f32x4 w1h = *(const f32x4*)&sP[100 + d];
    const f32x4 bh  = *(const f32x4*)&sP[200 + d];
    const f32x4 w0l = *(const f32x4*)&sP[300 + d];
    const f32x4 w1l = *(const f32x4*)&sP[400 + d];
    const f32x4 bl  = *(const f32x4*)&sP[500 + d];

    float* out_hi = out + (size_t)(e * N_ + n0) * D_;
    float* out_lo = out + (size_t)E_ * N_ * D_ + (size_t)(e * N_ + n0) * D_;

#pragma unroll 8
    for (int it = 0; it < TN / 16; ++it) {
        const int r0 = it * 16 + w * 4 + h;
        const float2 za = sZ2[r0];
        const float2 zb = sZ2[r0 + 2];
        f32x4 oha = za.x * w0h + za.y * w1h + bh;
        f32x4 ohb = zb.x * w0h + zb.y * w1h + bh;
        f32x4 ola = za.x * w0l + za.y * w1l + bl;
        f32x4 olb = zb.x * w0l + zb.y * w1l + bl;
        if (act) {
            const size_t off = (size_t)r0 * D_ + (size_t)d;
            *(f32x4*)&out_hi[off]          = oha;
            *(f32x4*)&out_hi[off + 2 * D_] = ohb;
            *(f32x4*)&out_lo[off]          = ola;
            *(f32x4*)&out_lo[off + 2 * D_] = olb;
        }
    }
}

extern "C" void kernel_launch(void* const* d_in, const int* in_sizes, int n_in,
                              void* d_out, int out_size, void* d_ws, size_t ws_size,
                              hipStream_t stream) {
    const float* inputs      = (const float*)d_in[0];
    const int*   randsamples = (const int*)d_in[1];
    const float* enc_w0 = (const float*)d_in[2];
    const float* enc_b0 = (const float*)d_in[3];
    const float* hi_w0  = (const float*)d_in[4];
    const float* hi_b0  = (const float*)d_in[5];
    const float* lo_w0  = (const float*)d_in[6];
    const float* lo_b0  = (const float*)d_in[7];
    const float* enc_w1 = (const float*)d_in[8];
    const float* enc_b1 = (const float*)d_in[9];
    const float* hi_w1  = (const float*)d_in[10];
    const float* hi_b1  = (const float*)d_in[11];
    const float* lo_w1  = (const float*)d_in[12];
    const float* lo_b1  = (const float*)d_in[13];
    const float* enc_w2 = (const float*)d_in[14];
    const float* enc_b2 = (const float*)d_in[15];
    const float* hi_w2  = (const float*)d_in[16];
    const float* hi_b2  = (const float*)d_in[17];
    const float* lo_w2  = (const float*)d_in[18];
    const float* lo_b2  = (const float*)d_in[19];

    float* ws  = (float*)d_ws;
    float* out = (float*)d_out;

    const size_t need_full = (size_t)(CMB_FLOATS + Z_FLOATS + T_FLOATS) * 4;
    const size_t need_t    = (size_t)(CMB_FLOATS + T_FLOATS) * 4;

    float* cmb = ws;

    if (ws_size >= need_full) {
        float*  zbuf = ws + CMB_FLOATS;
        float*  T    = ws + CMB_FLOATS + Z_FLOATS;
        prep_kernel<true><<<E_ + 256, 128, 0, stream>>>(
            inputs, enc_w0, enc_b0, enc_w1, enc_b1, enc_w2, enc_b2,
            hi_w0, hi_b0, hi_w1, hi_b1, hi_w2, hi_b2,
            lo_w0, lo_b0, lo_w1, lo_b1, lo_w2, lo_b2, cmb, T);
        z_kernel<<<E_ * NTILES, 256, 0, stream>>>(
            cmb, randsamples, T, (float2*)zbuf);
        rancoders_store<<<NB_STORE, 256, 0, stream>>>(
            cmb, (const float2*)zbuf, out);
    } else if (ws_size >= need_t) {
        float* T = ws + CMB_FLOATS;
        prep_kernel<true><<<E_ + 256, 128, 0, stream>>>(
            inputs, enc_w0, enc_b0, enc_w1, enc_b1, enc_w2, enc_b2,
            hi_w0, hi_b0, hi_w1, hi_b1, hi_w2, hi_b2,
            lo_w0, lo_b0, lo_w1, lo_b1, lo_w2, lo_b2, cmb, T);
        rancoders_mono<true><<<E_ * NTILES, 256, 0, stream>>>(
            inputs, randsamples, cmb, T, out);
    } else {
        prep_kernel<false><<<E_, 128, 0, stream>>>(
            inputs, enc_w0, enc_b0, enc_w1, enc_b1, enc_w2, enc_b2,
            hi_w0, hi_b0, hi_w1, hi_b1, hi_w2, hi_b2,
            lo_w0, lo_b0, lo_w1, lo_b1, lo_w2, lo_b2, cmb, nullptr);
        rancoders_mono<false><<<E_ * NTILES, 256, 0, stream>>>(
            inputs, randsamples, cmb, nullptr, out);
    }
}

// Round 11
// 149.376 us; speedup vs baseline: 1.2014x; 1.2014x over previous
//
#include <hip/hip_runtime.h>

// Problem constants
#define E_  100
#define F_  10
#define D_  100
#define N_  8192
#define TN  256          // n-tile per block
#define NTILES (N_ / TN) // 32
#define CHUNK 64         // rows staged in LDS per copy-out round

typedef float f32x4 __attribute__((ext_vector_type(4)));

// d_ws float layout:
//   per-estimator combined params, e = 0..99, stride WS_PER_E:
//     [0..199]   Whi (2 x 100, a-major)   [200..299] bhi
//     [300..499] Wlo (2 x 100)            [500..599] blo
//     [600..619] Wenc (10 x 2, f-major)   [620..621] benc
//   then transposed inputs at OFF_T: inputs_T[d][n], 100 x 8192
#define OFF_WHI  0
#define OFF_BHI  200
#define OFF_WLO  300
#define OFF_BLO  500
#define OFF_WENC 600
#define OFF_BENC 620
#define WS_PER_E 624
#define OFF_T    (E_ * WS_PER_E)                  // 62400 floats
#define WS_NEED_BYTES ((size_t)(OFF_T + D_ * N_) * 4)  // 3,539,200 B

// ---------------------------------------------------------------------------
// Prep kernel: blocks 0..99 fold estimator MLPs into affine maps;
// blocks 100..355 transpose inputs (8192x100 -> 100x8192), 128n x 25d tiles.
// ---------------------------------------------------------------------------
template <bool DO_TRANSPOSE>
__global__ __launch_bounds__(128) void prep_kernel(
    const float* __restrict__ inputs,
    const float* __restrict__ enc_w0, const float* __restrict__ enc_b0,
    const float* __restrict__ enc_w1, const float* __restrict__ enc_b1,
    const float* __restrict__ enc_w2, const float* __restrict__ enc_b2,
    const float* __restrict__ hi_w0,  const float* __restrict__ hi_b0,
    const float* __restrict__ hi_w1,  const float* __restrict__ hi_b1,
    const float* __restrict__ hi_w2,  const float* __restrict__ hi_b2,
    const float* __restrict__ lo_w0,  const float* __restrict__ lo_b0,
    const float* __restrict__ lo_w1,  const float* __restrict__ lo_b1,
    const float* __restrict__ lo_w2,  const float* __restrict__ lo_b2,
    float* __restrict__ ws)
{
    const int t = threadIdx.x;

    if (DO_TRANSPOSE && blockIdx.x >= E_) {
        // transpose tile: 128 consecutive n, 25 consecutive d
        const int bi = blockIdx.x - E_;          // 0..255
        const int n0 = (bi >> 2) * 128;
        const int d0 = (bi & 3) * 25;
        float* T = ws + OFF_T;
        const float* rowp = inputs + (size_t)(n0 + t) * D_ + d0;
#pragma unroll 5
        for (int j = 0; j < 25; ++j)
            T[(size_t)(d0 + j) * N_ + n0 + t] = rowp[j];
        return;
    }

    const int e = blockIdx.x;
    float* wsE = ws + (size_t)e * WS_PER_E;

    // ---------------- encoder: (10x5)@(5x2)@(2x2) -------------------------
    {
        const float* w0 = enc_w0 + e * 50;  // 10x5
        const float* w1 = enc_w1 + e * 10;  // 5x2
        const float* w2 = enc_w2 + e * 4;   // 2x2
        const float* b0 = enc_b0 + e * 5;
        const float* b1 = enc_b1 + e * 2;
        const float* b2 = enc_b2 + e * 2;

        __shared__ float sW01[20];  // [f][g] = w0@w1
        __shared__ float sB01[2];
        if (t < 20) {
            int f = t >> 1, g = t & 1;
            float s = 0.f;
            for (int k = 0; k < 5; ++k) s += w0[f * 5 + k] * w1[k * 2 + g];
            sW01[t] = s;
        }
        if (t < 2) {
            float s = b1[t];
            for (int k = 0; k < 5; ++k) s += b0[k] * w1[k * 2 + t];
            sB01[t] = s;
        }
        __syncthreads();
        if (t < 20) {
            int f = t >> 1, g2 = t & 1;
            wsE[OFF_WENC + t] = sW01[f * 2 + 0] * w2[0 * 2 + g2]
                              + sW01[f * 2 + 1] * w2[1 * 2 + g2];
        }
        if (t < 2) {
            wsE[OFF_BENC + t] = sB01[0] * w2[0 * 2 + t] + sB01[1] * w2[1 * 2 + t] + b2[t];
        }
        __syncthreads();
    }

    // ---------------- decoders: (2x25)@(25x50)@(50x100) -------------------
    __shared__ float sT[100];  // [a][c] = w0@w1  (2 x 50)
    __shared__ float sU[50];   // bias through layer 1
    for (int dec = 0; dec < 2; ++dec) {
        const float* w0 = (dec ? lo_w0 : hi_w0) + e * 50;    // 2x25
        const float* w1 = (dec ? lo_w1 : hi_w1) + e * 1250;  // 25x50
        const float* w2 = (dec ? lo_w2 : hi_w2) + e * 5000;  // 50x100
        const float* b0 = (dec ? lo_b0 : hi_b0) + e * 25;
        const float* b1 = (dec ? lo_b1 : hi_b1) + e * 50;
        const float* b2 = (dec ? lo_b2 : hi_b2) + e * 100;
        float* W = wsE + (dec ? OFF_WLO : OFF_WHI);
        float* B = wsE + (dec ? OFF_BLO : OFF_BHI);

        for (int i = t; i < 100; i += blockDim.x) {
            int a = i / 50, c = i % 50;
            float s = 0.f;
            for (int b = 0; b < 25; ++b) s += w0[a * 25 + b] * w1[b * 50 + c];
            sT[i] = s;
        }
        for (int i = t; i < 50; i += blockDim.x) {
            float s = b1[i];
            for (int b = 0; b < 25; ++b) s += b0[b] * w1[b * 50 + i];
            sU[i] = s;
        }
        __syncthreads();
        for (int i = t; i < 200; i += blockDim.x) {
            int a = i / 100, d = i % 100;
            float s = 0.f;
            for (int c = 0; c < 50; ++c) s += sT[a * 50 + c] * w2[c * 100 + d];
            W[i] = s;
        }
        for (int i = t; i < 100; i += blockDim.x) {
            float s = b2[i];
            for (int c = 0; c < 50; ++c) s += sU[c] * w2[c * 100 + i];
            B[i] = s;
        }
        __syncthreads();  // before sT/sU reuse by next decoder
    }
}

// ---------------------------------------------------------------------------
// Main kernel (R6 structure): per (e, n-tile): gather -> z -> LDS-staged
// chunks -> dense copy-out. ONLY change vs R6: copy-out stores are
// NONTEMPORAL. Every 64B line is fully covered by a single wave instruction
// (dense aligned 1024B wave-stores), so nt cannot cause partial-line RMW;
// it only skips L2 allocation for the 655MB one-shot output stream.
// ---------------------------------------------------------------------------
template <bool USE_T>
__global__ __launch_bounds__(256) void rancoders_main(
    const float* __restrict__ inputs,      // [N, D]
    const int*   __restrict__ randsamples, // [E, F]
    const float* __restrict__ ws,
    float* __restrict__ out)               // [hi: E*N*D][lo: E*N*D]
{
    const int e    = blockIdx.x >> 5;       // / NTILES
    const int tile = blockIdx.x & (NTILES - 1);
    const int n0   = tile * TN;
    const int t    = threadIdx.x;

    __shared__ __align__(16) float sP[WS_PER_E];
    __shared__ int    sIdx[F_];
    __shared__ float2 sZ2[TN];
    __shared__ __align__(16) float sStage[CHUNK * D_];   // 25,600 B

    const float* wsE = ws + (size_t)e * WS_PER_E;
    for (int i = t; i < 622; i += 256) sP[i] = wsE[i];
    if (t < F_) sIdx[t] = randsamples[e * F_ + t];
    __syncthreads();

    // ---- phase 1: latent z for this thread's row ----
    {
        float z0 = sP[OFF_BENC + 0];
        float z1 = sP[OFF_BENC + 1];
        if (USE_T) {
            const float* T = ws + OFF_T;
#pragma unroll
            for (int f = 0; f < F_; ++f) {
                float v = T[(size_t)sIdx[f] * N_ + n0 + t];  // coalesced
                z0 += v * sP[OFF_WENC + 2 * f + 0];
                z1 += v * sP[OFF_WENC + 2 * f + 1];
            }
        } else {
            const float* row = inputs + (size_t)(n0 + t) * D_;
#pragma unroll
            for (int f = 0; f < F_; ++f) {
                float v = row[sIdx[f]];
                z0 += v * sP[OFF_WENC + 2 * f + 0];
                z1 += v * sP[OFF_WENC + 2 * f + 1];
            }
        }
        sZ2[t] = make_float2(z0, z1);
    }

    // ---- phase 2 prep: per-lane weight registers ----
    const int w    = t >> 6;          // wave 0..3
    const int l    = t & 63;
    const int h    = l >> 5;          // half-wave 0/1
    const int dq   = l & 31;          // 0..31; 25..31 masked
    const bool act = (dq < 25);
    const int d    = (act ? dq : 24) * 4;   // clamp for safe LDS reads

    const f32x4 w0h = *(const f32x4*)&sP[OFF_WHI + d];
    const f32x4 w1h = *(const f32x4*)&sP[OFF_WHI + 100 + d];
    const f32x4 bh  = *(const f32x4*)&sP[OFF_BHI + d];
    const f32x4 w0l = *(const f32x4*)&sP[OFF_WLO + d];
    const f32x4 w1l = *(const f32x4*)&sP[OFF_WLO + 100 + d];
    const f32x4 bl  = *(const f32x4*)&sP[OFF_BLO + d];

    __syncthreads();

    float* out_hi = out + (size_t)(e * N_ + n0) * D_;
    float* out_lo = out + (size_t)E_ * N_ * D_ + (size_t)(e * N_ + n0) * D_;

    for (int half = 0; half < 2; ++half) {
        const f32x4 w0 = half ? w0l : w0h;
        const f32x4 w1 = half ? w1l : w1h;
        const f32x4 bb = half ? bl  : bh;
        float* dst_base = half ? out_lo : out_hi;

        for (int c = 0; c < TN / CHUNK; ++c) {
            // -- compute chunk rows [c*64, c*64+64) into LDS stage --
#pragma unroll
            for (int it = 0; it < CHUNK / 16; ++it) {
                const int rl = it * 16 + w * 4 + h;       // local row 0..63
                const float2 za = sZ2[c * CHUNK + rl];
                const float2 zb = sZ2[c * CHUNK + rl + 2];
                f32x4 oa = za.x * w0 + za.y * w1 + bb;
                f32x4 ob = zb.x * w0 + zb.y * w1 + bb;
                if (act) {
                    *(f32x4*)&sStage[rl * D_ + d]       = oa;
                    *(f32x4*)&sStage[(rl + 2) * D_ + d] = ob;
                }
            }
            __syncthreads();

            // -- dense copy-out: 1600 quads, all-lane NONTEMPORAL stores --
            float* dst = dst_base + (size_t)(c * CHUNK) * D_;
#pragma unroll
            for (int k = 0; k < 7; ++k) {
                const int q = k * 256 + t;
                if (q < (CHUNK * D_) / 4) {
                    f32x4 v = *(const f32x4*)&sStage[q * 4];
                    __builtin_nontemporal_store(v, (f32x4*)&dst[(size_t)q * 4]);
                }
            }
            __syncthreads();   // before stage reuse
        }
    }
}

extern "C" void kernel_launch(void* const* d_in, const int* in_sizes, int n_in,
                              void* d_out, int out_size, void* d_ws, size_t ws_size,
                              hipStream_t stream) {
    const float* inputs      = (const float*)d_in[0];
    const int*   randsamples = (const int*)d_in[1];
    const float* enc_w0 = (const float*)d_in[2];
    const float* enc_b0 = (const float*)d_in[3];
    const float* hi_w0  = (const float*)d_in[4];
    const float* hi_b0  = (const float*)d_in[5];
    const float* lo_w0  = (const float*)d_in[6];
    const float* lo_b0  = (const float*)d_in[7];
    const float* enc_w1 = (const float*)d_in[8];
    const float* enc_b1 = (const float*)d_in[9];
    const float* hi_w1  = (const float*)d_in[10];
    const float* hi_b1  = (const float*)d_in[11];
    const float* lo_w1  = (const float*)d_in[12];
    const float* lo_b1  = (const float*)d_in[13];
    const float* enc_w2 = (const float*)d_in[14];
    const float* enc_b2 = (const float*)d_in[15];
    const float* hi_w2  = (const float*)d_in[16];
    const float* hi_b2  = (const float*)d_in[17];
    const float* lo_w2  = (const float*)d_in[18];
    const float* lo_b2  = (const float*)d_in[19];

    float* ws  = (float*)d_ws;
    float* out = (float*)d_out;

    const bool use_t = (ws_size >= WS_NEED_BYTES);

    if (use_t) {
        prep_kernel<true><<<E_ + 256, 128, 0, stream>>>(
            inputs,
            enc_w0, enc_b0, enc_w1, enc_b1, enc_w2, enc_b2,
            hi_w0, hi_b0, hi_w1, hi_b1, hi_w2, hi_b2,
            lo_w0, lo_b0, lo_w1, lo_b1, lo_w2, lo_b2, ws);
        rancoders_main<true><<<E_ * NTILES, 256, 0, stream>>>(
            inputs, randsamples, ws, out);
    } else {
        prep_kernel<false><<<E_, 128, 0, stream>>>(
            inputs,
            enc_w0, enc_b0, enc_w1, enc_b1, enc_w2, enc_b2,
            hi_w0, hi_b0, hi_w1, hi_b1, hi_w2, hi_b2,
            lo_w0, lo_b0, lo_w1, lo_b1, lo_w2, lo_b2, ws);
        rancoders_main<false><<<E_ * NTILES, 256, 0, stream>>>(
            inputs, randsamples, ws, out);
    }
}